// Round 10
// baseline (7248.277 us; speedup 1.0000x reference)
//
#include <hip/hip_runtime.h>

// Recurrent spiking LIF network: T=64, B=32, NE=4096, NI=1024, N=5120.
// Spikes exactly {0,1}; fp64 accumulation => spike-identical to the fp64
// numpy reference (verified rounds 2/5/6/7/8/9: absmax 0.0).
//
// Round-10: 4 neurons/thread x 8 batches (same 64-VGPR acc class as the
// round-9 winner; round-8 taught us not to exceed ~64 VGPR of acc).
//  - block 256 = 64 n-lanes x 4 j-groups (wave-uniform jh -> broadcast
//    LDS reads, 0 conflicts). Each ds_read_b128 feeds 16 FMAs:
//    LDS pipe 32 -> 16 us/step. cvt tax ~12% of fma cycles.
//  - a block's 256 neurons are ALL E-targets (bx<16) or ALL I-targets:
//    one base row pointer + u*64*stride offsets; 4 j-groups reuse each
//    weight row through L1.
//  - G=32 k-split, CHUNK=160 staging, round-2 write pattern (41 MB).

#define NE 4096
#define NI 1024
#define NN 5120
#define BB 32
#define JH 8         // batches per thread
#define NU 4         // neurons per thread
#define CHUNK 160    // k-elements per LDS stage: 32*160*4 = 20 KB

// ---------------- matvec partial kernel ----------------
// grid: (NN/256, G), block 256. Thread (tn = t&63, jg = t>>6) owns
// neurons {bx*256 + u*64 + tn, u=0..3} x batches [jg*8, jg*8+8).
template <int KR>
__global__ __launch_bounds__(256) void mv_kernel(
    const float* __restrict__ W_ee, const float* __restrict__ W_ei,
    const float* __restrict__ W_ie, const float* __restrict__ W_ii,
    const float* __restrict__ sd,    // [BB][NN] spikes fp32 (0.0/1.0)
    double* __restrict__ partial)    // [G][BB][NN]
{
    __shared__ float s_l[BB][CHUNK];
    const int t  = threadIdx.x;
    const int tn = t & 63;
    const int jh = (t >> 6) << 3;              // 0,8,16,24
    const int n0 = blockIdx.x * 256 + tn;      // first owned neuron
    const int kb0 = blockIdx.y * KR;

    double acc[NU][JH];
#pragma unroll
    for (int u = 0; u < NU; ++u)
#pragma unroll
        for (int j = 0; j < JH; ++j) acc[u][j] = 0.0;

    // whole block targets E (n<NE) or I: single base pointer + u*64*stride
    const bool isE = (n0 < NE);
    const int nr = isE ? n0 : n0 - NE;
    const float* __restrict__ rowE = isE ? (W_ee + (size_t)nr * NE)
                                         : (W_ei + (size_t)nr * NE);
    const float* __restrict__ rowI = isE ? (W_ie + (size_t)nr * NI)
                                         : (W_ii + (size_t)nr * NI);

    for (int pass = 0; pass < KR / CHUNK; ++pass) {
        const int kb = kb0 + pass * CHUNK;

        if (pass) __syncthreads();
        // stage 32 x 160 fp32 spikes, float4-vectorized (1280 quads / 256 thr)
        for (int f = t; f < BB * (CHUNK / 4); f += 256) {
            const int j = f / (CHUNK / 4);
            const int q = f - j * (CHUNK / 4);
            *reinterpret_cast<float4*>(&s_l[j][q * 4]) =
                *reinterpret_cast<const float4*>(sd + (size_t)j * NN + kb + q * 4);
        }
        __syncthreads();

        int aEnd = NE - kb;                    // E/I source boundary
        if (aEnd < 0) aEnd = 0;
        if (aEnd > CHUNK) aEnd = CHUNK;        // always a multiple of 4

        // ---- excitatory sources ----
        for (int kk = 0; kk < aEnd; kk += 4) {
            double w[NU][4];
#pragma unroll
            for (int u = 0; u < NU; ++u) {
                const float4 wf = *reinterpret_cast<const float4*>(
                    rowE + (size_t)u * 64 * NE + kb + kk);
                w[u][0] = (double)wf.x; w[u][1] = (double)wf.y;
                w[u][2] = (double)wf.z; w[u][3] = (double)wf.w;
            }
#pragma unroll
            for (int j = 0; j < JH; ++j) {
                const float4 sv = *reinterpret_cast<const float4*>(&s_l[jh + j][kk]);
                const double s0 = (double)sv.x, s1 = (double)sv.y,
                             s2 = (double)sv.z, s3 = (double)sv.w;
#pragma unroll
                for (int u = 0; u < NU; ++u)
                    acc[u][j] += w[u][0] * s0 + w[u][1] * s1
                               + w[u][2] * s2 + w[u][3] * s3;
            }
        }
        // ---- inhibitory sources ----
        for (int kk = aEnd; kk < CHUNK; kk += 4) {
            const int ki = kb + kk - NE;
            double w[NU][4];
#pragma unroll
            for (int u = 0; u < NU; ++u) {
                const float4 wf = *reinterpret_cast<const float4*>(
                    rowI + (size_t)u * 64 * NI + ki);
                w[u][0] = (double)wf.x; w[u][1] = (double)wf.y;
                w[u][2] = (double)wf.z; w[u][3] = (double)wf.w;
            }
#pragma unroll
            for (int j = 0; j < JH; ++j) {
                const float4 sv = *reinterpret_cast<const float4*>(&s_l[jh + j][kk]);
                const double s0 = (double)sv.x, s1 = (double)sv.y,
                             s2 = (double)sv.z, s3 = (double)sv.w;
#pragma unroll
                for (int u = 0; u < NU; ++u)
                    acc[u][j] += w[u][0] * s0 + w[u][1] * s1
                               + w[u][2] * s2 + w[u][3] * s3;
            }
        }
    }

#pragma unroll
    for (int u = 0; u < NU; ++u)
#pragma unroll
        for (int j = 0; j < JH; ++j)
            partial[((size_t)blockIdx.y * BB + jh + j) * NN + n0 + u * 64]
                = acc[u][j];
}

// ---------------- LIF update kernel ----------------
template <int G>
__global__ __launch_bounds__(256) void upd_kernel(
    const float* __restrict__ ext_exc,   // [T][BB][NE]
    const float* __restrict__ ext_inh,   // [T][BB][NI]
    const double* __restrict__ partial,  // [G][BB][NN]
    double* __restrict__ v,              // [BB][NN]
    float* __restrict__ sd,              // [BB][NN] fp32 spikes
    float* __restrict__ out,             // [T][BB][NN]
    int t)
{
    const int idx = blockIdx.x * 256 + threadIdx.x;   // < BB*NN
    const int b = idx / NN;
    const int n = idx - b * NN;

    const float ext = (n < NE)
        ? ext_exc[((size_t)t * BB + b) * NE + n]
        : ext_inh[((size_t)t * BB + b) * NI + (n - NE)];

    double acc = (double)ext;
#pragma unroll
    for (int g = 0; g < G; ++g)
        acc += partial[((size_t)g * BB + b) * NN + n];

    const double vv = v[idx] * 0.9 + acc;
    const double sp = (vv > 1.0) ? 1.0 : 0.0;
    out[(size_t)t * BB * NN + idx] = (float)sp;
    v[idx] = vv * (1.0 - sp);
    sd[idx] = (float)sp;
}

extern "C" void kernel_launch(void* const* d_in, const int* in_sizes, int n_in,
                              void* d_out, int out_size, void* d_ws, size_t ws_size,
                              hipStream_t stream) {
    const float* ext_exc = (const float*)d_in[0];
    const float* ext_inh = (const float*)d_in[1];
    const float* W_ee = (const float*)d_in[2];
    const float* W_ei = (const float*)d_in[3];
    const float* W_ie = (const float*)d_in[4];
    const float* W_ii = (const float*)d_in[5];
    float* out = (float*)d_out;

    const int T = in_sizes[0] / (BB * NE);   // 64

    const size_t SN = (size_t)BB * NN;       // 163840
    double* v = (double*)d_ws;               // [BB][NN] fp64
    float* sd = (float*)(v + SN);            // [BB][NN] fp32
    double* partial = (double*)(sd + SN);    // [G][BB][NN] fp64
    const size_t stateBytes = SN * 12;       // v + sd, ~2.0 MB

    // largest k-split G whose fp64 partial fits (rounds 2-9 proved 44MB fits)
    int G = 32;
    while (G > 8 && stateBytes + (size_t)G * SN * sizeof(double) > ws_size) G >>= 1;

    hipMemsetAsync(d_ws, 0, stateBytes, stream);   // v = 0, spikes = 0

    for (int t = 0; t < T; ++t) {
        switch (G) {
            case 32:
                mv_kernel<160> <<<dim3(NN/256, 32), 256, 0, stream>>>(W_ee, W_ei, W_ie, W_ii, sd, partial);
                upd_kernel<32><<<(int)(SN/256), 256, 0, stream>>>(ext_exc, ext_inh, partial, v, sd, out, t);
                break;
            case 16:
                mv_kernel<320> <<<dim3(NN/256, 16), 256, 0, stream>>>(W_ee, W_ei, W_ie, W_ii, sd, partial);
                upd_kernel<16><<<(int)(SN/256), 256, 0, stream>>>(ext_exc, ext_inh, partial, v, sd, out, t);
                break;
            default:
                mv_kernel<640> <<<dim3(NN/256, 8), 256, 0, stream>>>(W_ee, W_ei, W_ie, W_ii, sd, partial);
                upd_kernel<8> <<<(int)(SN/256), 256, 0, stream>>>(ext_exc, ext_inh, partial, v, sd, out, t);
                break;
        }
    }
}

// Round 11
// 5568.285 us; speedup vs baseline: 1.3017x; 1.3017x over previous
//
#include <hip/hip_runtime.h>

// Recurrent spiking LIF network: T=64, B=32, NE=4096, NI=1024, N=5120.
// Spikes exactly {0,1}; fp64 accumulation => spike-identical to the fp64
// numpy reference (verified rounds 2/5/6/7/8/9/10: absmax 0.0).
//
// Round-11: round-9 winner (2n x 16j, 64-VGPR acc) with two stall fixes:
//  - 1280 blocks of 128 thr = EXACTLY 5 blocks/CU (round 9's 640 blocks
//    = 2.5/CU gave a 3-vs-2 block tail imbalance).
//  - explicit 1-quad-ahead register prefetch of the two weight float4s
//    (L3 latency ~600cy was exposed at the top of each k-quad body).
// Round-10 lesson kept: do NOT widen to 4 weight streams / short j-loop.

#define NE 4096
#define NI 1024
#define NN 5120
#define HN 2560      // NN/2
#define BB 32
#define JH 16        // batches per thread
#define CHUNK 160    // k-elements per LDS stage: 32*160*4 = 20 KB

// ---------------- matvec partial kernel ----------------
// grid: (HN/64, G), block 128. Thread (tn = t&63, jh = (t>>6)*16) owns
// neurons {nA = bx*64+tn, nA+2560} x batches [jh, jh+16) over KR sources.
template <int KR>
__global__ __launch_bounds__(128) void mv_kernel(
    const float* __restrict__ W_ee, const float* __restrict__ W_ei,
    const float* __restrict__ W_ie, const float* __restrict__ W_ii,
    const float* __restrict__ sd,    // [BB][NN] spikes fp32 (0.0/1.0)
    double* __restrict__ partial)    // [G][BB][NN]
{
    __shared__ float s_l[BB][CHUNK];
    const int t  = threadIdx.x;
    const int tn = t & 63;
    const int jh = (t >> 6) << 4;              // 0 or 16
    const int nA = blockIdx.x * 64 + tn;       // 0..2559 (< NE: E-target)
    const int nB = nA + HN;                    // 2560..5119 (mixed)
    const int kb0 = blockIdx.y * KR;

    double accA[JH], accB[JH];
#pragma unroll
    for (int j = 0; j < JH; ++j) { accA[j] = 0.0; accB[j] = 0.0; }

    const float* __restrict__ rEA = W_ee + (size_t)nA * NE;   // nA < NE
    const float* __restrict__ rIA = W_ie + (size_t)nA * NI;
    const float* __restrict__ rEB = (nB < NE) ? (W_ee + (size_t)nB * NE)
                                              : (W_ei + (size_t)(nB - NE) * NE);
    const float* __restrict__ rIB = (nB < NE) ? (W_ie + (size_t)nB * NI)
                                              : (W_ii + (size_t)(nB - NE) * NI);

    for (int pass = 0; pass < KR / CHUNK; ++pass) {
        const int kb = kb0 + pass * CHUNK;

        if (pass) __syncthreads();
        // stage 32 x 160 fp32 spikes, float4-vectorized (1280 quads / 128 thr)
        for (int f = t; f < BB * (CHUNK / 4); f += 128) {
            const int j = f / (CHUNK / 4);
            const int q = f - j * (CHUNK / 4);
            *reinterpret_cast<float4*>(&s_l[j][q * 4]) =
                *reinterpret_cast<const float4*>(sd + (size_t)j * NN + kb + q * 4);
        }
        __syncthreads();

        int aEnd = NE - kb;                    // E/I source boundary
        if (aEnd < 0) aEnd = 0;
        if (aEnd > CHUNK) aEnd = CHUNK;        // always a multiple of 4

        // ---- excitatory sources (prefetched weight pipeline) ----
        if (aEnd > 0) {
            const float* pA = rEA + kb;
            const float* pB = rEB + kb;
            float4 wa = *reinterpret_cast<const float4*>(pA);
            float4 wb = *reinterpret_cast<const float4*>(pB);
            for (int kk = 0; kk < aEnd; kk += 4) {
                const float4 wac = wa, wbc = wb;
                if (kk + 4 < aEnd) {           // uniform branch
                    wa = *reinterpret_cast<const float4*>(pA + kk + 4);
                    wb = *reinterpret_cast<const float4*>(pB + kk + 4);
                }
                const double wa0 = (double)wac.x, wa1 = (double)wac.y,
                             wa2 = (double)wac.z, wa3 = (double)wac.w;
                const double wb0 = (double)wbc.x, wb1 = (double)wbc.y,
                             wb2 = (double)wbc.z, wb3 = (double)wbc.w;
#pragma unroll
                for (int j = 0; j < JH; ++j) {
                    const float4 sv = *reinterpret_cast<const float4*>(&s_l[jh + j][kk]);
                    const double s0 = (double)sv.x, s1 = (double)sv.y,
                                 s2 = (double)sv.z, s3 = (double)sv.w;
                    accA[j] += wa0 * s0 + wa1 * s1 + wa2 * s2 + wa3 * s3;
                    accB[j] += wb0 * s0 + wb1 * s1 + wb2 * s2 + wb3 * s3;
                }
            }
        }
        // ---- inhibitory sources (prefetched weight pipeline) ----
        if (aEnd < CHUNK) {
            const float* pA = rIA + (kb + aEnd - NE);
            const float* pB = rIB + (kb + aEnd - NE);
            const int len = CHUNK - aEnd;
            float4 wa = *reinterpret_cast<const float4*>(pA);
            float4 wb = *reinterpret_cast<const float4*>(pB);
            for (int kk = 0; kk < len; kk += 4) {
                const float4 wac = wa, wbc = wb;
                if (kk + 4 < len) {            // uniform branch
                    wa = *reinterpret_cast<const float4*>(pA + kk + 4);
                    wb = *reinterpret_cast<const float4*>(pB + kk + 4);
                }
                const double wa0 = (double)wac.x, wa1 = (double)wac.y,
                             wa2 = (double)wac.z, wa3 = (double)wac.w;
                const double wb0 = (double)wbc.x, wb1 = (double)wbc.y,
                             wb2 = (double)wbc.z, wb3 = (double)wbc.w;
#pragma unroll
                for (int j = 0; j < JH; ++j) {
                    const float4 sv = *reinterpret_cast<const float4*>(&s_l[jh + j][aEnd + kk]);
                    const double s0 = (double)sv.x, s1 = (double)sv.y,
                                 s2 = (double)sv.z, s3 = (double)sv.w;
                    accA[j] += wa0 * s0 + wa1 * s1 + wa2 * s2 + wa3 * s3;
                    accB[j] += wb0 * s0 + wb1 * s1 + wb2 * s2 + wb3 * s3;
                }
            }
        }
    }

#pragma unroll
    for (int j = 0; j < JH; ++j) {
        const size_t base = ((size_t)blockIdx.y * BB + jh + j) * NN;
        partial[base + nA] = accA[j];
        partial[base + nB] = accB[j];
    }
}

// ---------------- LIF update kernel ----------------
template <int G>
__global__ __launch_bounds__(256) void upd_kernel(
    const float* __restrict__ ext_exc,   // [T][BB][NE]
    const float* __restrict__ ext_inh,   // [T][BB][NI]
    const double* __restrict__ partial,  // [G][BB][NN]
    double* __restrict__ v,              // [BB][NN]
    float* __restrict__ sd,              // [BB][NN] fp32 spikes
    float* __restrict__ out,             // [T][BB][NN]
    int t)
{
    const int idx = blockIdx.x * 256 + threadIdx.x;   // < BB*NN
    const int b = idx / NN;
    const int n = idx - b * NN;

    const float ext = (n < NE)
        ? ext_exc[((size_t)t * BB + b) * NE + n]
        : ext_inh[((size_t)t * BB + b) * NI + (n - NE)];

    double acc = (double)ext;
#pragma unroll
    for (int g = 0; g < G; ++g)
        acc += partial[((size_t)g * BB + b) * NN + n];

    const double vv = v[idx] * 0.9 + acc;
    const double sp = (vv > 1.0) ? 1.0 : 0.0;
    out[(size_t)t * BB * NN + idx] = (float)sp;
    v[idx] = vv * (1.0 - sp);
    sd[idx] = (float)sp;
}

extern "C" void kernel_launch(void* const* d_in, const int* in_sizes, int n_in,
                              void* d_out, int out_size, void* d_ws, size_t ws_size,
                              hipStream_t stream) {
    const float* ext_exc = (const float*)d_in[0];
    const float* ext_inh = (const float*)d_in[1];
    const float* W_ee = (const float*)d_in[2];
    const float* W_ei = (const float*)d_in[3];
    const float* W_ie = (const float*)d_in[4];
    const float* W_ii = (const float*)d_in[5];
    float* out = (float*)d_out;

    const int T = in_sizes[0] / (BB * NE);   // 64

    const size_t SN = (size_t)BB * NN;       // 163840
    double* v = (double*)d_ws;               // [BB][NN] fp64
    float* sd = (float*)(v + SN);            // [BB][NN] fp32
    double* partial = (double*)(sd + SN);    // [G][BB][NN] fp64
    const size_t stateBytes = SN * 12;       // v + sd, ~2.0 MB

    // largest k-split G whose fp64 partial fits (rounds 2-10 proved 44MB fits)
    int G = 32;
    while (G > 8 && stateBytes + (size_t)G * SN * sizeof(double) > ws_size) G >>= 1;

    hipMemsetAsync(d_ws, 0, stateBytes, stream);   // v = 0, spikes = 0

    for (int t = 0; t < T; ++t) {
        switch (G) {
            case 32:
                mv_kernel<160> <<<dim3(HN/64, 32), 128, 0, stream>>>(W_ee, W_ei, W_ie, W_ii, sd, partial);
                upd_kernel<32><<<(int)(SN/256), 256, 0, stream>>>(ext_exc, ext_inh, partial, v, sd, out, t);
                break;
            case 16:
                mv_kernel<320> <<<dim3(HN/64, 16), 128, 0, stream>>>(W_ee, W_ei, W_ie, W_ii, sd, partial);
                upd_kernel<16><<<(int)(SN/256), 256, 0, stream>>>(ext_exc, ext_inh, partial, v, sd, out, t);
                break;
            default:
                mv_kernel<640> <<<dim3(HN/64, 8), 128, 0, stream>>>(W_ee, W_ei, W_ie, W_ii, sd, partial);
                upd_kernel<8> <<<(int)(SN/256), 256, 0, stream>>>(ext_exc, ext_inh, partial, v, sd, out, t);
                break;
        }
    }
}